// Round 5
// baseline (92.494 us; speedup 1.0000x reference)
//
#include <hip/hip_runtime.h>

// B=32, S=512, H=256, T=MAX_MEL=2000, DUR_MAX=8
// d_out: output [B,T,H] f32 (16,384,000 floats) then mel_len [B] as floats.
//
// Single fused dispatch, 2016 blocks x 256 threads:
//   1. shuffle-scan cumsum of the batch's 512 durations -> s_cum (LDS),
//   2. lanes 0..31 run PARALLEL exact upper_bound searches (while-loop,
//      <=10 steps — 9 fixed steps was an off-by-one: 513 outcomes need 10)
//      -> s_idx[32],
//   3. copy loop: 8 independent (load f32x4 -> nt store) iterations per wave,
//      no dependent search in the chain -> deep MLP of global loads.
// XCD swizzle: block id&7 = XCD under round-robin dispatch; each XCD owns
// 4 batches (2 MB of x) so x stays L2-resident despite the write stream.
constexpr int B_ = 32;
constexpr int S_ = 512;
constexpr int H_ = 256;
constexpr int T_ = 2000;
constexpr int F4 = H_ / 4;                    // 64 float4 per row
constexpr int RPB = 32;                       // t-rows per block
constexpr int NBLK_T = (T_ + RPB - 1) / RPB;  // 63
constexpr int GRID = NBLK_T * B_;             // 2016

typedef float f32x4 __attribute__((ext_vector_type(4)));

__global__ __launch_bounds__(256) void lenreg_fused_kernel(
    const f32x4* __restrict__ x,        // [B,S,64]
    const int* __restrict__ dur,        // [B,S]
    const int* __restrict__ max_len_p,  // [1]
    f32x4* __restrict__ out,            // [B,T,64]
    float* __restrict__ mel_len_out)    // [B]
{
    const int id = blockIdx.x;
    const int xcd = id & 7;                   // target XCD (round-robin heuristic)
    const int j = id >> 3;                    // 0..251
    const int b = xcd * 4 + j / NBLK_T;       // 4 batches per XCD
    const int chunk = j % NBLK_T;             // 0..62
    const int t0 = chunk * RPB;

    const int tid = threadIdx.x;
    const int lane = tid & 63;
    const int wave = tid >> 6;

    __shared__ int s_cum[S_];
    __shared__ int s_wsum[4];
    __shared__ int s_idx[RPB];

    // --- cumsum of dur[b][:] : 2 elements/thread, shuffle scan ---
    const int2 d2 = ((const int2*)(dur + b * S_))[tid];
    const int pair = d2.x + d2.y;
    int scan = pair;
#pragma unroll
    for (int off = 1; off < 64; off <<= 1) {
        const int y = __shfl_up(scan, off);
        if (lane >= off) scan += y;
    }
    if (lane == 63) s_wsum[wave] = scan;
    __syncthreads();
    int wprefix = 0;
#pragma unroll
    for (int w = 0; w < 4; ++w) wprefix += (w < wave) ? s_wsum[w] : 0;
    const int excl = wprefix + scan - pair;   // exclusive prefix of element 2*tid
    s_cum[2 * tid]     = excl + d2.x;
    s_cum[2 * tid + 1] = excl + pair;
    __syncthreads();

    // --- 32 parallel exact searches: s_idx[r] for t = t0+r ---
    if (tid < RPB) {
        const int t = t0 + tid;
        int lo = 0, hi = S_;
        if (t < T_) {
            while (lo < hi) {                 // exact upper_bound, <=10 steps
                const int mid = (lo + hi) >> 1;
                if (s_cum[mid] <= t) lo = mid + 1; else hi = mid;
            }
        }
        s_idx[tid] = lo < (S_ - 1) ? lo : (S_ - 1);
    }
    if (chunk == 0 && tid == 64) {            // wave 1: overlaps wave 0's search
        const int total = s_cum[S_ - 1];
        const int ml = max_len_p[0];
        mel_len_out[b] = (float)(total < ml ? total : ml);
    }
    __syncthreads();

    // --- streaming copy: 8 independent row copies per wave ---
    const f32x4* __restrict__ x_b = x + (size_t)b * S_ * F4;
    f32x4* __restrict__ out_b = out + (size_t)b * T_ * F4;
#pragma unroll
    for (int i = 0; i < RPB / 4; ++i) {
        const int t = t0 + i * 4 + wave;
        if (t < T_) {
            const int idx = s_idx[i * 4 + wave];
            const f32x4 v = x_b[(size_t)idx * F4 + lane];
            __builtin_nontemporal_store(v, &out_b[(size_t)t * F4 + lane]);
        }
    }
}

extern "C" void kernel_launch(void* const* d_in, const int* in_sizes, int n_in,
                              void* d_out, int out_size, void* d_ws, size_t ws_size,
                              hipStream_t stream) {
    const f32x4* x = (const f32x4*)d_in[0];
    const int* duration = (const int*)d_in[1];
    const int* max_len_p = (const int*)d_in[2];

    float* out = (float*)d_out;                        // [B,T,H]
    float* mel_len_out = out + (size_t)B_ * T_ * H_;   // [B] as floats

    lenreg_fused_kernel<<<GRID, 256, 0, stream>>>(
        x, duration, max_len_p, (f32x4*)out, mel_len_out);
}

// Round 6
// 89.281 us; speedup vs baseline: 1.0360x; 1.0360x over previous
//
#include <hip/hip_runtime.h>

// B=32, S=512, H=256, T=MAX_MEL=2000, DUR_MAX=8
// d_out: output [B,T,H] f32 then mel_len [B] as floats.
//
// SCATTER formulation (single dispatch):
//   row s of x maps to output rows [cum[s-1], cum[s]) — load each x row
//   from HBM exactly once into registers, store it dur[s] times (nt).
//   -> compulsory traffic only: read 16.8 MB x + ~3 MB dur, write 65.5 MB.
//   No binary search, no dependence on x staying L2-resident.
// Per batch: 32 scatter blocks (16 s-rows each, 4 rows/wave) + 16 tail
// blocks (125 t-rows each) that fill [total, T) with row S-1; tail blocks
// below `total` exit after the scan, so any duration data is handled.
constexpr int B_ = 32;
constexpr int S_ = 512;
constexpr int H_ = 256;
constexpr int T_ = 2000;
constexpr int F4 = H_ / 4;                 // 64 float4 per row
constexpr int RPS = 16;                    // s-rows per scatter block
constexpr int N_SCAT = S_ / RPS;           // 32
constexpr int TAIL_CHUNK = 125;
constexpr int N_TAIL = (T_ + TAIL_CHUNK - 1) / TAIL_CHUNK;  // 16

typedef float f32x4 __attribute__((ext_vector_type(4)));

__global__ __launch_bounds__(256) void lenreg_scatter_kernel(
    const f32x4* __restrict__ x,        // [B,S,64]
    const int* __restrict__ dur,        // [B,S]
    const int* __restrict__ max_len_p,  // [1]
    f32x4* __restrict__ out,            // [B,T,64]
    float* __restrict__ mel_len_out)    // [B]
{
    const int b = blockIdx.y;
    const int role = blockIdx.x;              // 0..31 scatter, 32..47 tail
    const int tid = threadIdx.x;
    const int lane = tid & 63;
    const int wave = tid >> 6;

    __shared__ int s_cum[S_];
    __shared__ int s_wsum[4];

    // --- cumsum of dur[b][:]: 2 elems/thread shuffle scan + LDS combine ---
    const int2 d2 = ((const int2*)(dur + b * S_))[tid];
    const int pair = d2.x + d2.y;
    int scan = pair;
#pragma unroll
    for (int off = 1; off < 64; off <<= 1) {
        const int y = __shfl_up(scan, off);
        if (lane >= off) scan += y;
    }
    if (lane == 63) s_wsum[wave] = scan;
    __syncthreads();
    int wprefix = 0;
#pragma unroll
    for (int w = 0; w < 4; ++w) wprefix += (w < wave) ? s_wsum[w] : 0;
    const int excl = wprefix + scan - pair;
    s_cum[2 * tid]     = excl + d2.x;
    s_cum[2 * tid + 1] = excl + pair;
    __syncthreads();

    const int total = s_cum[S_ - 1];
    const f32x4* __restrict__ x_b = x + (size_t)b * S_ * F4;
    f32x4* __restrict__ out_b = out + (size_t)b * T_ * F4;

    if (role < N_SCAT) {
        // --- scatter: wave owns 4 consecutive source rows ---
        const int s0 = role * RPS + wave * (RPS / 4);
        f32x4 v[RPS / 4];
#pragma unroll
        for (int i = 0; i < RPS / 4; ++i)      // hoisted: 4 independent loads
            v[i] = x_b[(size_t)(s0 + i) * F4 + lane];
#pragma unroll
        for (int i = 0; i < RPS / 4; ++i) {
            const int s = s0 + i;
            const int lo = s ? s_cum[s - 1] : 0;
            int hi = s_cum[s]; if (hi > T_) hi = T_;
            for (int t = lo; t < hi; ++t)      // wave-uniform trip count <=8
                __builtin_nontemporal_store(v[i], &out_b[(size_t)t * F4 + lane]);
        }
    } else {
        // --- tail: fill [total, T) with row S-1 ---
        const int j = role - N_SCAT;
        if (j == 0 && tid == 0) {
            const int ml = max_len_p[0];
            mel_len_out[b] = (float)(total < ml ? total : ml);
        }
        int t_begin = j * TAIL_CHUNK;
        int t_end = t_begin + TAIL_CHUNK; if (t_end > T_) t_end = T_;
        if (t_begin < total) t_begin = total;
        if (t_begin < t_end) {
            const f32x4 v = x_b[(size_t)(S_ - 1) * F4 + lane];
            for (int t = t_begin + wave; t < t_end; t += 4)
                __builtin_nontemporal_store(v, &out_b[(size_t)t * F4 + lane]);
        }
    }
}

extern "C" void kernel_launch(void* const* d_in, const int* in_sizes, int n_in,
                              void* d_out, int out_size, void* d_ws, size_t ws_size,
                              hipStream_t stream) {
    const f32x4* x = (const f32x4*)d_in[0];
    const int* duration = (const int*)d_in[1];
    const int* max_len_p = (const int*)d_in[2];

    float* out = (float*)d_out;                        // [B,T,H]
    float* mel_len_out = out + (size_t)B_ * T_ * H_;   // [B] as floats

    dim3 grid(N_SCAT + N_TAIL, B_);                    // 48 x 32 = 1536 blocks
    lenreg_scatter_kernel<<<grid, 256, 0, stream>>>(
        x, duration, max_len_p, (f32x4*)out, mel_len_out);
}

// Round 7
// 86.913 us; speedup vs baseline: 1.0642x; 1.0272x over previous
//
#include <hip/hip_runtime.h>

// B=32, S=512, H=256, T=MAX_MEL=2000, DUR_MAX=8
// d_out: output [B,T,H] f32 then mel_len [B] as floats.
//
// SCATTER formulation (single dispatch):
//   row s of x maps to output rows [cum[s-1], cum[s]) — load each x row
//   from HBM exactly once into registers, store it dur[s] times.
//   Compulsory traffic only: read 16.8 MB x + dur, write 65.5 MB.
// R7 A/B vs R6: (1) plain stores instead of nontemporal (x is read once,
// so nt's L2-protection is void; if nt throttled the 65.5 MB write stream
// this is a straight win), (2) x-row loads issued BEFORE the scan to
// overlap global-load latency with the shuffle scan.
constexpr int B_ = 32;
constexpr int S_ = 512;
constexpr int H_ = 256;
constexpr int T_ = 2000;
constexpr int F4 = H_ / 4;                 // 64 float4 per row
constexpr int RPS = 16;                    // s-rows per scatter block
constexpr int N_SCAT = S_ / RPS;           // 32
constexpr int TAIL_CHUNK = 125;
constexpr int N_TAIL = (T_ + TAIL_CHUNK - 1) / TAIL_CHUNK;  // 16

typedef float f32x4 __attribute__((ext_vector_type(4)));

__global__ __launch_bounds__(256) void lenreg_scatter_kernel(
    const f32x4* __restrict__ x,        // [B,S,64]
    const int* __restrict__ dur,        // [B,S]
    const int* __restrict__ max_len_p,  // [1]
    f32x4* __restrict__ out,            // [B,T,64]
    float* __restrict__ mel_len_out)    // [B]
{
    const int b = blockIdx.y;
    const int role = blockIdx.x;              // 0..31 scatter, 32..47 tail
    const int tid = threadIdx.x;
    const int lane = tid & 63;
    const int wave = tid >> 6;

    __shared__ int s_cum[S_];
    __shared__ int s_wsum[4];

    const f32x4* __restrict__ x_b = x + (size_t)b * S_ * F4;
    f32x4* __restrict__ out_b = out + (size_t)b * T_ * F4;

    // --- issue x loads FIRST: independent of the scan, overlap latencies ---
    f32x4 v[RPS / 4];
    int s0 = 0;
    if (role < N_SCAT) {
        s0 = role * RPS + wave * (RPS / 4);
#pragma unroll
        for (int i = 0; i < RPS / 4; ++i)
            v[i] = x_b[(size_t)(s0 + i) * F4 + lane];
    } else {
        v[0] = x_b[(size_t)(S_ - 1) * F4 + lane];
    }

    // --- cumsum of dur[b][:]: 2 elems/thread shuffle scan + LDS combine ---
    const int2 d2 = ((const int2*)(dur + b * S_))[tid];
    const int pair = d2.x + d2.y;
    int scan = pair;
#pragma unroll
    for (int off = 1; off < 64; off <<= 1) {
        const int y = __shfl_up(scan, off);
        if (lane >= off) scan += y;
    }
    if (lane == 63) s_wsum[wave] = scan;
    __syncthreads();
    int wprefix = 0;
#pragma unroll
    for (int w = 0; w < 4; ++w) wprefix += (w < wave) ? s_wsum[w] : 0;
    const int excl = wprefix + scan - pair;
    s_cum[2 * tid]     = excl + d2.x;
    s_cum[2 * tid + 1] = excl + pair;
    __syncthreads();

    const int total = s_cum[S_ - 1];

    if (role < N_SCAT) {
        // --- scatter: wave owns 4 consecutive source rows ---
#pragma unroll
        for (int i = 0; i < RPS / 4; ++i) {
            const int s = s0 + i;
            const int lo = s ? s_cum[s - 1] : 0;
            int hi = s_cum[s]; if (hi > T_) hi = T_;
            for (int t = lo; t < hi; ++t)      // wave-uniform trip count <=8
                out_b[(size_t)t * F4 + lane] = v[i];
        }
    } else {
        // --- tail: fill [total, T) with row S-1 ---
        const int j = role - N_SCAT;
        if (j == 0 && tid == 0) {
            const int ml = max_len_p[0];
            mel_len_out[b] = (float)(total < ml ? total : ml);
        }
        int t_begin = j * TAIL_CHUNK;
        int t_end = t_begin + TAIL_CHUNK; if (t_end > T_) t_end = T_;
        if (t_begin < total) t_begin = total;
        for (int t = t_begin + wave; t < t_end; t += 4)
            out_b[(size_t)t * F4 + lane] = v[0];
    }
}

extern "C" void kernel_launch(void* const* d_in, const int* in_sizes, int n_in,
                              void* d_out, int out_size, void* d_ws, size_t ws_size,
                              hipStream_t stream) {
    const f32x4* x = (const f32x4*)d_in[0];
    const int* duration = (const int*)d_in[1];
    const int* max_len_p = (const int*)d_in[2];

    float* out = (float*)d_out;                        // [B,T,H]
    float* mel_len_out = out + (size_t)B_ * T_ * H_;   // [B] as floats

    dim3 grid(N_SCAT + N_TAIL, B_);                    // 48 x 32 = 1536 blocks
    lenreg_scatter_kernel<<<grid, 256, 0, stream>>>(
        x, duration, max_len_p, (f32x4*)out, mel_len_out);
}